// Round 2
// baseline (908.116 us; speedup 1.0000x reference)
//
#include <hip/hip_runtime.h>
#include <math.h>

#define N_NODES 50000
#define N_PAD   50048              // rows padded to multiple of 64
#define N_EDGES 1600000
#define DIM     128
#define RCUT    5.0f
#define NGROUP  (N_PAD / 64)       // 782 groups of 64 nodes
#define NSUB    16                 // b-subchunks for partial2/pbase
#define XPAD    136                // LDS X tile row stride in bf16 (272 B)
#define MAXNB   1024               // partial/pbase sized for this many blocks

typedef __attribute__((ext_vector_type(8))) __bf16 bf16x8;
typedef __attribute__((ext_vector_type(4))) float  f32x4;

// ---------------- bf16 helpers ----------------
__device__ __forceinline__ float bf_lo(unsigned int u) { return __uint_as_float(u << 16); }
__device__ __forceinline__ float bf_hi(unsigned int u) { return __uint_as_float(u & 0xffff0000u); }
__device__ __forceinline__ unsigned short f2bf(float x) {
    unsigned int u = __float_as_uint(x);
    u += 0x7fffu + ((u >> 16) & 1u);   // round-to-nearest-even
    return (unsigned short)(u >> 16);
}

// ---------------- manual grid barrier (all blocks resident) ----------------
__device__ __forceinline__ void gsync(int* bar, int idx, int nb) {
    __syncthreads();
    if (threadIdx.x == 0) {
        __threadfence();   // device-scope release: L2 writeback for cross-XCD visibility
        __hip_atomic_fetch_add(&bar[idx], 1, __ATOMIC_RELAXED, __HIP_MEMORY_SCOPE_AGENT);
        while (__hip_atomic_load(&bar[idx], __ATOMIC_RELAXED, __HIP_MEMORY_SCOPE_AGENT) < nb)
            __builtin_amdgcn_s_sleep(2);
        __threadfence();   // acquire: invalidate caches before consuming
    }
    __syncthreads();
}

// ---------------- fused layer body: gather 64 nodes -> LDS -> GEMM ---------
#define EDGE2(mx, mf, rr)                                        \
    do {                                                         \
        float ff = __int_as_float(mf);                           \
        a0 = fmaf(ff, bf_lo(rr), a0);                            \
        a1 = fmaf(ff, bf_hi(rr), a1);                            \
    } while (0)

__device__ __forceinline__ void layer_body(
        const unsigned short* __restrict__ cur,
        const unsigned short* __restrict__ vb,
        const int2*  __restrict__ meta,
        const int*   __restrict__ off,
        const uint4* __restrict__ wfrag,
        const float* __restrict__ bias,
        unsigned short* __restrict__ out_bf,
        float* __restrict__ out_f,
        int last, int g, unsigned short* xlds) {
    int tid  = threadIdx.x;
    int wv   = tid >> 6, lane = tid & 63;
    int n0   = g * 64 + wv * 8;

    int offidx = n0 + ((lane < 9) ? lane : 8);
    if (offidx > N_NODES) offidx = N_NODES;
    int myoff = off[offidx];

    const char* basec = (const char*)cur + lane * 4;

    #pragma unroll 1
    for (int q = 0; q < 8; ++q) {
        int nl = wv * 8 + q;
        int n  = n0 + q;
        float a0 = 0.f, a1 = 0.f;
        if (n < N_NODES) {
            unsigned vv = *(const unsigned*)((const char*)vb + (size_t)n * (DIM * 2) + lane * 4);
            a0 = bf_lo(vv); a1 = bf_hi(vv);
            int beg = __builtin_amdgcn_readlane(myoff, q);
            int end = __builtin_amdgcn_readlane(myoff, q + 1);
            int c = beg;
            if ((c & 1) && c < end) {
                int2 m = meta[c];
                unsigned rr = *(const unsigned*)(basec + (unsigned)m.x);
                EDGE2(m.x, m.y, rr);
                ++c;
            }
            for (; c + 16 <= end; c += 16) {
                int4 m0 = *(const int4*)(meta + c);
                int4 m1 = *(const int4*)(meta + c + 2);
                int4 m2 = *(const int4*)(meta + c + 4);
                int4 m3 = *(const int4*)(meta + c + 6);
                int4 m4 = *(const int4*)(meta + c + 8);
                int4 m5 = *(const int4*)(meta + c + 10);
                int4 m6 = *(const int4*)(meta + c + 12);
                int4 m7 = *(const int4*)(meta + c + 14);
                unsigned r0  = *(const unsigned*)(basec + (unsigned)m0.x);
                unsigned r1  = *(const unsigned*)(basec + (unsigned)m0.z);
                unsigned r2  = *(const unsigned*)(basec + (unsigned)m1.x);
                unsigned r3  = *(const unsigned*)(basec + (unsigned)m1.z);
                unsigned r4  = *(const unsigned*)(basec + (unsigned)m2.x);
                unsigned r5  = *(const unsigned*)(basec + (unsigned)m2.z);
                unsigned r6  = *(const unsigned*)(basec + (unsigned)m3.x);
                unsigned r7  = *(const unsigned*)(basec + (unsigned)m3.z);
                unsigned r8  = *(const unsigned*)(basec + (unsigned)m4.x);
                unsigned r9  = *(const unsigned*)(basec + (unsigned)m4.z);
                unsigned r10 = *(const unsigned*)(basec + (unsigned)m5.x);
                unsigned r11 = *(const unsigned*)(basec + (unsigned)m5.z);
                unsigned r12 = *(const unsigned*)(basec + (unsigned)m6.x);
                unsigned r13 = *(const unsigned*)(basec + (unsigned)m6.z);
                unsigned r14 = *(const unsigned*)(basec + (unsigned)m7.x);
                unsigned r15 = *(const unsigned*)(basec + (unsigned)m7.z);
                EDGE2(m0.x, m0.y, r0);  EDGE2(m0.z, m0.w, r1);
                EDGE2(m1.x, m1.y, r2);  EDGE2(m1.z, m1.w, r3);
                EDGE2(m2.x, m2.y, r4);  EDGE2(m2.z, m2.w, r5);
                EDGE2(m3.x, m3.y, r6);  EDGE2(m3.z, m3.w, r7);
                EDGE2(m4.x, m4.y, r8);  EDGE2(m4.z, m4.w, r9);
                EDGE2(m5.x, m5.y, r10); EDGE2(m5.z, m5.w, r11);
                EDGE2(m6.x, m6.y, r12); EDGE2(m6.z, m6.w, r13);
                EDGE2(m7.x, m7.y, r14); EDGE2(m7.z, m7.w, r15);
            }
            if (c + 8 <= end) {
                int4 m0 = *(const int4*)(meta + c);
                int4 m1 = *(const int4*)(meta + c + 2);
                int4 m2 = *(const int4*)(meta + c + 4);
                int4 m3 = *(const int4*)(meta + c + 6);
                unsigned r0 = *(const unsigned*)(basec + (unsigned)m0.x);
                unsigned r1 = *(const unsigned*)(basec + (unsigned)m0.z);
                unsigned r2 = *(const unsigned*)(basec + (unsigned)m1.x);
                unsigned r3 = *(const unsigned*)(basec + (unsigned)m1.z);
                unsigned r4 = *(const unsigned*)(basec + (unsigned)m2.x);
                unsigned r5 = *(const unsigned*)(basec + (unsigned)m2.z);
                unsigned r6 = *(const unsigned*)(basec + (unsigned)m3.x);
                unsigned r7 = *(const unsigned*)(basec + (unsigned)m3.z);
                EDGE2(m0.x, m0.y, r0); EDGE2(m0.z, m0.w, r1);
                EDGE2(m1.x, m1.y, r2); EDGE2(m1.z, m1.w, r3);
                EDGE2(m2.x, m2.y, r4); EDGE2(m2.z, m2.w, r5);
                EDGE2(m3.x, m3.y, r6); EDGE2(m3.z, m3.w, r7);
                c += 8;
            }
            for (; c < end; ++c) {
                int2 m = meta[c];
                unsigned rr = *(const unsigned*)(basec + (unsigned)m.x);
                EDGE2(m.x, m.y, rr);
            }
        }
        *(unsigned*)(xlds + nl * XPAD + lane * 2) =
            (unsigned)f2bf(a0) | ((unsigned)f2bf(a1) << 16);
    }
    __syncthreads();

    // ---- GEMM: wave wv -> rows (wv>>1)*16..+15, col-half (wv&1) ----
    int quad = lane >> 4, l16 = lane & 15;
    int rb = wv >> 1, nh = wv & 1;
    f32x4 acc[4];
    #pragma unroll
    for (int j = 0; j < 4; ++j) acc[j] = (f32x4){0.f, 0.f, 0.f, 0.f};

    const unsigned short* xp = xlds + (rb * 16 + l16) * XPAD + quad * 8;
    #pragma unroll
    for (int kk = 0; kk < 4; ++kk) {
        bf16x8 af = *(const bf16x8*)(xp + kk * 32);
        #pragma unroll
        for (int j = 0; j < 4; ++j) {
            uint4 w = wfrag[(kk * 8 + nh * 4 + j) * 64 + lane];
            bf16x8 bfr = __builtin_bit_cast(bf16x8, w);
            acc[j] = __builtin_amdgcn_mfma_f32_16x16x32_bf16(af, bfr, acc[j], 0, 0, 0);
        }
    }

    int orow0 = g * 64 + rb * 16 + quad * 4;
    #pragma unroll
    for (int j = 0; j < 4; ++j) {
        int col = (nh * 4 + j) * 16 + l16;
        float b = bias[col];
        #pragma unroll
        for (int r = 0; r < 4; ++r) {
            int orow = orow0 + r;
            if (orow < N_NODES) {
                float val = fmaxf(acc[j][r] + b, 0.f);
                if (last) out_f[(size_t)orow * DIM + col] = val;
                else      out_bf[(size_t)orow * DIM + col] = f2bf(val);
            }
        }
    }
}

// ---------------- the whole pipeline in one kernel ----------------
__global__ __launch_bounds__(512, 8) void mega_kernel(
        const float* __restrict__ v, const float* __restrict__ e,
        const int* __restrict__ src, const int* __restrict__ dst,
        const float* __restrict__ Aw, const float* __restrict__ Ab,
        const float* __restrict__ rs, const float* __restrict__ sigma,
        float* __restrict__ out,
        int2* __restrict__ meta, unsigned short* __restrict__ bufV,
        unsigned short* __restrict__ bufA, unsigned short* __restrict__ bufB,
        uint4* __restrict__ wfrag, int* __restrict__ off, int* __restrict__ goff,
        int* __restrict__ partial, int* __restrict__ partial2,
        int* __restrict__ pbase, int* __restrict__ bar) {
    __shared__ __align__(16) char smem[64 * XPAD * 2];   // 17408 B, reused per phase
    const int bid = blockIdx.x, tid = threadIdx.x;
    const int NB = gridDim.x, GT = NB * 512;
    const int gid = bid * 512 + tid;
    const int CH  = (N_EDGES + NB - 1) / NB;
    const int ebeg = bid * CH;
    const int eend = (ebeg + CH < N_EDGES) ? ebeg + CH : N_EDGES;

    // ---- P0a: v -> bf16 ----
    for (int i = gid; i < N_NODES * DIM / 4; i += GT) {
        float4 x = ((const float4*)v)[i];
        uint2 o;
        o.x = (unsigned)f2bf(x.x) | ((unsigned)f2bf(x.y) << 16);
        o.y = (unsigned)f2bf(x.z) | ((unsigned)f2bf(x.w) << 16);
        ((uint2*)bufV)[i] = o;
    }
    // ---- P0b: W fragments ----
    if (gid < 2048) {
        int t = gid;
        int lane = t & 63, nt = (t >> 6) & 7, kk = t >> 9;
        int n  = nt * 16 + (lane & 15);
        int k0 = kk * 32 + (lane >> 4) * 8;
        unsigned short h[8];
        #pragma unroll
        for (int i = 0; i < 8; ++i) h[i] = f2bf(Aw[n * DIM + k0 + i]);
        uint4 o;
        o.x = h[0] | ((unsigned)h[1] << 16); o.y = h[2] | ((unsigned)h[3] << 16);
        o.z = h[4] | ((unsigned)h[5] << 16); o.w = h[6] | ((unsigned)h[7] << 16);
        wfrag[t] = o;
    }
    // ---- P0c: group-64 histogram for this block's edge chunk ----
    {
        int* h = (int*)smem;                      // NGROUP ints
        for (int g = tid; g < NGROUP; g += 512) h[g] = 0;
        __syncthreads();
        for (int i = ebeg + tid; i < eend; i += 512)
            atomicAdd(&h[dst[i] >> 6], 1);
        __syncthreads();
        for (int g = tid; g < NGROUP; g += 512) partial[bid * NGROUP + g] = h[g];
    }
    gsync(bar, 0, NB);

    // ---- P1: partial2[NSUB][NGROUP] ----
    const int BS = (NB + NSUB - 1) / NSUB;
    for (int id = gid; id < NSUB * NGROUP; id += GT) {
        int bb = id / NGROUP, g = id - bb * NGROUP;
        int b0 = bb * BS, b1 = (b0 + BS < NB) ? b0 + BS : NB;
        int s = 0;
        for (int b = b0; b < b1; ++b) s += partial[b * NGROUP + g];
        partial2[bb * NGROUP + g] = s;
    }
    gsync(bar, 1, NB);

    // ---- P2: exclusive scan over group totals (block 0) ----
    if (bid == 0) {
        int* part = (int*)smem;                   // 512 ints
        int i0 = tid * 2;
        int vv[2]; int s = 0;
        #pragma unroll
        for (int k = 0; k < 2; ++k) {
            int i = i0 + k; int t = 0;
            if (i < NGROUP) {
                #pragma unroll
                for (int bb = 0; bb < NSUB; ++bb) t += partial2[bb * NGROUP + i];
            }
            vv[k] = t; s += t;
        }
        part[tid] = s; __syncthreads();
        for (int d = 1; d < 512; d <<= 1) {
            int val = (tid >= d) ? part[tid - d] : 0;
            __syncthreads(); part[tid] += val; __syncthreads();
        }
        int run = (tid == 0) ? 0 : part[tid - 1];
        #pragma unroll
        for (int k = 0; k < 2; ++k) {
            int i = i0 + k;
            if (i < NGROUP) { goff[i] = run; run += vv[k]; }
        }
        if (tid == 0) goff[NGROUP] = N_EDGES;
    }
    gsync(bar, 2, NB);

    // ---- P3: per-(block,group) bases ----
    for (int id = gid; id < NSUB * NGROUP; id += GT) {
        int bb = id / NGROUP, g = id - bb * NGROUP;
        int run = goff[g];
        for (int b2 = 0; b2 < bb; ++b2) run += partial2[b2 * NGROUP + g];
        int b0 = bb * BS, b1 = (b0 + BS < NB) ? b0 + BS : NB;
        for (int b = b0; b < b1; ++b) {
            pbase[b * NGROUP + g] = run;
            run += partial[b * NGROUP + g];
        }
    }
    gsync(bar, 3, NB);

    // ---- P4: reorder into group-64 CSR with 6-bit node tags ----
    {
        int* base = (int*)smem;                   // NGROUP
        int* cnt  = base + NGROUP;                // NGROUP
        for (int g = tid; g < NGROUP; g += 512) {
            base[g] = pbase[bid * NGROUP + g]; cnt[g] = 0;
        }
        __syncthreads();
        float rsv = rs[0], sg = sigma[0];
        int2* metaT = (int2*)bufA;
        for (int i = ebeg + tid; i < eend; i += 512) {
            float r  = e[i];
            float d  = r - rsv;
            float gauss = expf(-(d * d) / (sg * sg));
            float cut   = 0.5f * cosf(r * (float)(M_PI / (double)RCUT));
            cut = (r < RCUT) ? cut : 0.0f;
            float fe = gauss * cut;
            int dn = dst[i];
            int g  = dn >> 6;
            int lr = atomicAdd(&cnt[g], 1);
            metaT[base[g] + lr] = make_int2(src[i] * (DIM * 2) | ((dn & 63) << 24),
                                            __float_as_int(fe));
        }
    }
    gsync(bar, 4, NB);

    // ---- P5: 64-bin counting sort per group -> node-exact CSR ----
    for (int g = bid; g < NGROUP; g += NB) {
        __syncthreads();                          // protect smem reuse across iters
        int* c64 = (int*)smem; int* b64 = c64 + 64; int* cu64 = b64 + 64;
        const int2* metaT = (const int2*)bufA;
        int sbeg = goff[g], send = goff[g + 1];
        if (tid < 64) c64[tid] = 0;
        __syncthreads();
        for (int i = sbeg + tid; i < send; i += 512)
            atomicAdd(&c64[(metaT[i].x >> 24) & 63], 1);
        __syncthreads();
        if (tid == 0) {
            int run = 0;
            #pragma unroll
            for (int t = 0; t < 64; ++t) { b64[t] = run; cu64[t] = run; run += c64[t]; }
        }
        __syncthreads();
        if (tid < 64) {
            int node = g * 64 + tid;
            if (node <= N_NODES) off[node] = sbeg + b64[tid];
        }
        __syncthreads();
        for (int i = sbeg + tid; i < send; i += 512) {
            int2 m = metaT[i];
            int tag = (m.x >> 24) & 63;
            int lr = atomicAdd(&cu64[tag], 1);
            meta[sbeg + lr] = make_int2(m.x & 0x00FFFFFF, m.y);
        }
    }
    gsync(bar, 5, NB);

    // ---- P6..P8: three fused gather+GEMM layers ----
    unsigned short* xlds = (unsigned short*)smem;
    for (int L = 0; L < 3; ++L) {
        const unsigned short* curp = (L == 0) ? bufV : ((L == 1) ? bufB : bufA);
        unsigned short* outb = (L == 0) ? bufB : bufA;
        for (int g = bid; g < NGROUP; g += NB) {
            __syncthreads();                      // xlds reuse across iters
            layer_body(curp, bufV, meta, off, wfrag, Ab,
                       outb, out, (L == 2) ? 1 : 0, g, xlds);
        }
        if (L < 2) gsync(bar, 6 + L, NB);
    }
}

// ---------------------------------------------------------------------------
extern "C" void kernel_launch(void* const* d_in, const int* in_sizes, int n_in,
                              void* d_out, int out_size, void* d_ws, size_t ws_size,
                              hipStream_t stream) {
    const float* v     = (const float*)d_in[0];
    const float* e     = (const float*)d_in[1];
    const int*   src   = (const int*)  d_in[2];
    const int*   dst   = (const int*)  d_in[3];
    const float* Aw    = (const float*)d_in[4];
    const float* Ab    = (const float*)d_in[5];
    const float* rs    = (const float*)d_in[6];
    const float* sigma = (const float*)d_in[7];
    float* out = (float*)d_out;

    // ---- workspace layout (~51.5 MB) ----
    char* p = (char*)d_ws;
    int2*           meta  = (int2*)p;            p += (size_t)N_EDGES * 8;       // 12.8 MB (final CSR)
    unsigned short* bufV  = (unsigned short*)p;  p += (size_t)N_PAD * DIM * 2;   // 12.81 MB (pristine bf16 v)
    unsigned short* bufA  = (unsigned short*)p;  p += (size_t)N_PAD * DIM * 2;   // 12.81 MB (metaT / L1 out)
    unsigned short* bufB  = (unsigned short*)p;  p += (size_t)N_PAD * DIM * 2;   // 12.81 MB (partials / L0 out)
    uint4*          wfrag = (uint4*)p;           p += 2048 * 16;                 //  32 KB
    int*            off   = (int*)p;             p += (size_t)(N_NODES + 1) * 4;
    int*            goff  = (int*)p;             p += (NGROUP + 2) * 4;
    int*            bar   = (int*)p;             p += 16 * 4;                    // grid-barrier counters
    // aliases inside bufB (dead before L0's first write):
    int* partial  = (int*)bufB;                  // [MAXNB][NGROUP] = 3.2 MB
    int* partial2 = partial + MAXNB * NGROUP;    // [NSUB][NGROUP]  = 50 KB
    int* pbase    = partial2 + NSUB * NGROUP;    // [MAXNB][NGROUP] = 3.2 MB

    static int maxblk = 0;
    if (maxblk == 0) {
        if (hipOccupancyMaxActiveBlocksPerMultiprocessor(&maxblk, mega_kernel, 512, 0)
                != hipSuccess || maxblk <= 0)
            maxblk = 2;   // conservative floor: LDS 17.4KB and <=64 VGPR guarantee >=2
    }
    int nb = maxblk * 256;          // 256 CUs on MI355X
    if (nb > NGROUP) nb = NGROUP;   // also guarantees nb <= MAXNB

    hipMemsetAsync(bar, 0, 16 * 4, stream);
    mega_kernel<<<nb, 512, 0, stream>>>(
        v, e, src, dst, Aw, Ab, rs, sigma, out,
        meta, bufV, bufA, bufB, wfrag, off, goff,
        partial, partial2, pbase, bar);
}

// Round 3
// 696.734 us; speedup vs baseline: 1.3034x; 1.3034x over previous
//
#include <hip/hip_runtime.h>
#include <math.h>

#define N_NODES 50000
#define N_PAD   50048              // rows padded to multiple of 64
#define N_EDGES 1600000
#define DIM     128
#define RCUT    5.0f
#define NGROUP  (N_PAD / 64)       // 782 groups of 64 nodes
#define NSUB    16                 // b-subchunks for partial2/pbase
#define XPAD    136                // LDS X tile row stride in bf16 (272 B)
#define MAXNB   1024               // partial/pbase sized for this many blocks
#define BSTRIDE 32                 // ints per barrier counter line (128 B)
#define NPHASE  9                  // barrier phases allocated

typedef __attribute__((ext_vector_type(8))) __bf16 bf16x8;
typedef __attribute__((ext_vector_type(4))) float  f32x4;

// ---------------- bf16 helpers ----------------
__device__ __forceinline__ float bf_lo(unsigned int u) { return __uint_as_float(u << 16); }
__device__ __forceinline__ float bf_hi(unsigned int u) { return __uint_as_float(u & 0xffff0000u); }
__device__ __forceinline__ unsigned short f2bf(float x) {
    unsigned int u = __float_as_uint(x);
    u += 0x7fffu + ((u >> 16) & 1u);   // round-to-nearest-even
    return (unsigned short)(u >> 16);
}

// ---------------- low-contention grid barrier (all blocks resident) --------
// Arrivals spread over 64 private cachelines; block 0 wave 0 aggregates
// (one reader per line); waiters poll a separate read-only release line.
__device__ __forceinline__ void gsync(int* arr, int* rel, int phase, int nb) {
    __syncthreads();
    int tid = threadIdx.x;
    if (blockIdx.x == 0) {
        if (tid == 0) {
            __threadfence();
            __hip_atomic_fetch_add(&arr[(phase * 64 + 0) * BSTRIDE], 1,
                                   __ATOMIC_RELAXED, __HIP_MEMORY_SCOPE_AGENT);
        }
        if (tid < 64) {
            int target = (nb + 63 - tid) / 64;   // #blocks with bid%64==tid
            int* cp = &arr[(phase * 64 + tid) * BSTRIDE];
            bool done = (target <= 0);
            while (!__all(done)) {
                if (!done)
                    done = __hip_atomic_load(cp, __ATOMIC_RELAXED,
                                             __HIP_MEMORY_SCOPE_AGENT) >= target;
                if (!__all(done)) __builtin_amdgcn_s_sleep(2);
            }
            if (tid == 0) {
                __threadfence();
                __hip_atomic_store(rel, phase + 1, __ATOMIC_RELEASE,
                                   __HIP_MEMORY_SCOPE_AGENT);
                __threadfence();
            }
        }
        __syncthreads();
    } else {
        if (tid == 0) {
            __threadfence();
            __hip_atomic_fetch_add(&arr[(phase * 64 + (blockIdx.x & 63)) * BSTRIDE], 1,
                                   __ATOMIC_RELAXED, __HIP_MEMORY_SCOPE_AGENT);
            while (__hip_atomic_load(rel, __ATOMIC_RELAXED,
                                     __HIP_MEMORY_SCOPE_AGENT) < phase + 1)
                __builtin_amdgcn_s_sleep(8);
            __threadfence();
        }
        __syncthreads();
    }
}

// ---------------- fused layer body: gather 64 nodes -> LDS -> GEMM ---------
#define EDGE2(mx, mf, rr)                                        \
    do {                                                         \
        float ff = __int_as_float(mf);                           \
        a0 = fmaf(ff, bf_lo(rr), a0);                            \
        a1 = fmaf(ff, bf_hi(rr), a1);                            \
    } while (0)

__device__ __forceinline__ void layer_body(
        const unsigned short* __restrict__ cur,
        const unsigned short* __restrict__ vb,
        const int2*  __restrict__ meta,
        const int*   __restrict__ off,
        const uint4* __restrict__ wfrag,
        const float* __restrict__ bias,
        unsigned short* __restrict__ out_bf,
        float* __restrict__ out_f,
        int last, int g, unsigned short* xlds) {
    int tid  = threadIdx.x;
    int wv   = tid >> 6, lane = tid & 63;
    int n0   = g * 64 + wv * 8;

    int offidx = n0 + ((lane < 9) ? lane : 8);
    if (offidx > N_NODES) offidx = N_NODES;
    int myoff = off[offidx];

    const char* basec = (const char*)cur + lane * 4;

    #pragma unroll 1
    for (int q = 0; q < 8; ++q) {
        int nl = wv * 8 + q;
        int n  = n0 + q;
        float a0 = 0.f, a1 = 0.f;
        if (n < N_NODES) {
            unsigned vv = *(const unsigned*)((const char*)vb + (size_t)n * (DIM * 2) + lane * 4);
            a0 = bf_lo(vv); a1 = bf_hi(vv);
            int beg = __builtin_amdgcn_readlane(myoff, q);
            int end = __builtin_amdgcn_readlane(myoff, q + 1);
            int c = beg;
            if ((c & 1) && c < end) {
                int2 m = meta[c];
                unsigned rr = *(const unsigned*)(basec + (unsigned)m.x);
                EDGE2(m.x, m.y, rr);
                ++c;
            }
            for (; c + 16 <= end; c += 16) {
                int4 m0 = *(const int4*)(meta + c);
                int4 m1 = *(const int4*)(meta + c + 2);
                int4 m2 = *(const int4*)(meta + c + 4);
                int4 m3 = *(const int4*)(meta + c + 6);
                int4 m4 = *(const int4*)(meta + c + 8);
                int4 m5 = *(const int4*)(meta + c + 10);
                int4 m6 = *(const int4*)(meta + c + 12);
                int4 m7 = *(const int4*)(meta + c + 14);
                unsigned r0  = *(const unsigned*)(basec + (unsigned)m0.x);
                unsigned r1  = *(const unsigned*)(basec + (unsigned)m0.z);
                unsigned r2  = *(const unsigned*)(basec + (unsigned)m1.x);
                unsigned r3  = *(const unsigned*)(basec + (unsigned)m1.z);
                unsigned r4  = *(const unsigned*)(basec + (unsigned)m2.x);
                unsigned r5  = *(const unsigned*)(basec + (unsigned)m2.z);
                unsigned r6  = *(const unsigned*)(basec + (unsigned)m3.x);
                unsigned r7  = *(const unsigned*)(basec + (unsigned)m3.z);
                unsigned r8  = *(const unsigned*)(basec + (unsigned)m4.x);
                unsigned r9  = *(const unsigned*)(basec + (unsigned)m4.z);
                unsigned r10 = *(const unsigned*)(basec + (unsigned)m5.x);
                unsigned r11 = *(const unsigned*)(basec + (unsigned)m5.z);
                unsigned r12 = *(const unsigned*)(basec + (unsigned)m6.x);
                unsigned r13 = *(const unsigned*)(basec + (unsigned)m6.z);
                unsigned r14 = *(const unsigned*)(basec + (unsigned)m7.x);
                unsigned r15 = *(const unsigned*)(basec + (unsigned)m7.z);
                EDGE2(m0.x, m0.y, r0);  EDGE2(m0.z, m0.w, r1);
                EDGE2(m1.x, m1.y, r2);  EDGE2(m1.z, m1.w, r3);
                EDGE2(m2.x, m2.y, r4);  EDGE2(m2.z, m2.w, r5);
                EDGE2(m3.x, m3.y, r6);  EDGE2(m3.z, m3.w, r7);
                EDGE2(m4.x, m4.y, r8);  EDGE2(m4.z, m4.w, r9);
                EDGE2(m5.x, m5.y, r10); EDGE2(m5.z, m5.w, r11);
                EDGE2(m6.x, m6.y, r12); EDGE2(m6.z, m6.w, r13);
                EDGE2(m7.x, m7.y, r14); EDGE2(m7.z, m7.w, r15);
            }
            if (c + 8 <= end) {
                int4 m0 = *(const int4*)(meta + c);
                int4 m1 = *(const int4*)(meta + c + 2);
                int4 m2 = *(const int4*)(meta + c + 4);
                int4 m3 = *(const int4*)(meta + c + 6);
                unsigned r0 = *(const unsigned*)(basec + (unsigned)m0.x);
                unsigned r1 = *(const unsigned*)(basec + (unsigned)m0.z);
                unsigned r2 = *(const unsigned*)(basec + (unsigned)m1.x);
                unsigned r3 = *(const unsigned*)(basec + (unsigned)m1.z);
                unsigned r4 = *(const unsigned*)(basec + (unsigned)m2.x);
                unsigned r5 = *(const unsigned*)(basec + (unsigned)m2.z);
                unsigned r6 = *(const unsigned*)(basec + (unsigned)m3.x);
                unsigned r7 = *(const unsigned*)(basec + (unsigned)m3.z);
                EDGE2(m0.x, m0.y, r0); EDGE2(m0.z, m0.w, r1);
                EDGE2(m1.x, m1.y, r2); EDGE2(m1.z, m1.w, r3);
                EDGE2(m2.x, m2.y, r4); EDGE2(m2.z, m2.w, r5);
                EDGE2(m3.x, m3.y, r6); EDGE2(m3.z, m3.w, r7);
                c += 8;
            }
            for (; c < end; ++c) {
                int2 m = meta[c];
                unsigned rr = *(const unsigned*)(basec + (unsigned)m.x);
                EDGE2(m.x, m.y, rr);
            }
        }
        *(unsigned*)(xlds + nl * XPAD + lane * 2) =
            (unsigned)f2bf(a0) | ((unsigned)f2bf(a1) << 16);
    }
    __syncthreads();

    // ---- GEMM: wave wv -> rows (wv>>1)*16..+15, col-half (wv&1) ----
    int quad = lane >> 4, l16 = lane & 15;
    int rb = wv >> 1, nh = wv & 1;
    f32x4 acc[4];
    #pragma unroll
    for (int j = 0; j < 4; ++j) acc[j] = (f32x4){0.f, 0.f, 0.f, 0.f};

    const unsigned short* xp = xlds + (rb * 16 + l16) * XPAD + quad * 8;
    #pragma unroll
    for (int kk = 0; kk < 4; ++kk) {
        bf16x8 af = *(const bf16x8*)(xp + kk * 32);
        #pragma unroll
        for (int j = 0; j < 4; ++j) {
            uint4 w = wfrag[(kk * 8 + nh * 4 + j) * 64 + lane];
            bf16x8 bfr = __builtin_bit_cast(bf16x8, w);
            acc[j] = __builtin_amdgcn_mfma_f32_16x16x32_bf16(af, bfr, acc[j], 0, 0, 0);
        }
    }

    int orow0 = g * 64 + rb * 16 + quad * 4;
    #pragma unroll
    for (int j = 0; j < 4; ++j) {
        int col = (nh * 4 + j) * 16 + l16;
        float b = bias[col];
        #pragma unroll
        for (int r = 0; r < 4; ++r) {
            int orow = orow0 + r;
            if (orow < N_NODES) {
                float val = fmaxf(acc[j][r] + b, 0.f);
                if (last) out_f[(size_t)orow * DIM + col] = val;
                else      out_bf[(size_t)orow * DIM + col] = f2bf(val);
            }
        }
    }
}

// ---------------- the whole pipeline in one kernel ----------------
__global__ __launch_bounds__(512, 8) void mega_kernel(
        const float* __restrict__ v, const float* __restrict__ e,
        const int* __restrict__ src, const int* __restrict__ dst,
        const float* __restrict__ Aw, const float* __restrict__ Ab,
        const float* __restrict__ rs, const float* __restrict__ sigma,
        float* __restrict__ out,
        int2* __restrict__ meta, unsigned short* __restrict__ bufV,
        unsigned short* __restrict__ bufA, unsigned short* __restrict__ bufB,
        uint4* __restrict__ wfrag, int* __restrict__ off, int* __restrict__ goff,
        int* __restrict__ partial, int* __restrict__ partial2,
        int* __restrict__ pbase, int* __restrict__ arr, int* __restrict__ rel) {
    __shared__ __align__(16) char smem[64 * XPAD * 2];   // 17408 B, reused per phase
    const int bid = blockIdx.x, tid = threadIdx.x;
    const int NB = gridDim.x, GT = NB * 512;
    const int gid = bid * 512 + tid;
    const int CH  = (N_EDGES + NB - 1) / NB;
    const int ebeg = bid * CH;
    const int eend = (ebeg + CH < N_EDGES) ? ebeg + CH : N_EDGES;

    // ---- P0a: v -> bf16 ----
    for (int i = gid; i < N_NODES * DIM / 4; i += GT) {
        float4 x = ((const float4*)v)[i];
        uint2 o;
        o.x = (unsigned)f2bf(x.x) | ((unsigned)f2bf(x.y) << 16);
        o.y = (unsigned)f2bf(x.z) | ((unsigned)f2bf(x.w) << 16);
        ((uint2*)bufV)[i] = o;
    }
    // ---- P0b: W fragments ----
    if (gid < 2048) {
        int t = gid;
        int lane = t & 63, nt = (t >> 6) & 7, kk = t >> 9;
        int n  = nt * 16 + (lane & 15);
        int k0 = kk * 32 + (lane >> 4) * 8;
        unsigned short h[8];
        #pragma unroll
        for (int i = 0; i < 8; ++i) h[i] = f2bf(Aw[n * DIM + k0 + i]);
        uint4 o;
        o.x = h[0] | ((unsigned)h[1] << 16); o.y = h[2] | ((unsigned)h[3] << 16);
        o.z = h[4] | ((unsigned)h[5] << 16); o.w = h[6] | ((unsigned)h[7] << 16);
        wfrag[t] = o;
    }
    // ---- P0c: group-64 histogram for this block's edge chunk ----
    {
        int* h = (int*)smem;                      // NGROUP ints
        for (int g = tid; g < NGROUP; g += 512) h[g] = 0;
        __syncthreads();
        for (int i = ebeg + tid; i < eend; i += 512)
            atomicAdd(&h[dst[i] >> 6], 1);
        __syncthreads();
        for (int g = tid; g < NGROUP; g += 512) partial[bid * NGROUP + g] = h[g];
    }
    gsync(arr, rel, 0, NB);

    // ---- P1: partial2[NSUB][NGROUP] ----
    const int BS = (NB + NSUB - 1) / NSUB;
    for (int id = gid; id < NSUB * NGROUP; id += GT) {
        int bb = id / NGROUP, g = id - bb * NGROUP;
        int b0 = bb * BS, b1 = (b0 + BS < NB) ? b0 + BS : NB;
        int s = 0;
        for (int b = b0; b < b1; ++b) s += partial[b * NGROUP + g];
        partial2[bb * NGROUP + g] = s;
    }
    gsync(arr, rel, 1, NB);

    // ---- P2: exclusive scan over group totals (block 0) ----
    if (bid == 0) {
        int* part = (int*)smem;                   // 512 ints
        int i0 = tid * 2;
        int vv[2]; int s = 0;
        #pragma unroll
        for (int k = 0; k < 2; ++k) {
            int i = i0 + k; int t = 0;
            if (i < NGROUP) {
                #pragma unroll
                for (int bb = 0; bb < NSUB; ++bb) t += partial2[bb * NGROUP + i];
            }
            vv[k] = t; s += t;
        }
        part[tid] = s; __syncthreads();
        for (int d = 1; d < 512; d <<= 1) {
            int val = (tid >= d) ? part[tid - d] : 0;
            __syncthreads(); part[tid] += val; __syncthreads();
        }
        int run = (tid == 0) ? 0 : part[tid - 1];
        #pragma unroll
        for (int k = 0; k < 2; ++k) {
            int i = i0 + k;
            if (i < NGROUP) { goff[i] = run; run += vv[k]; }
        }
        if (tid == 0) goff[NGROUP] = N_EDGES;
    }
    gsync(arr, rel, 2, NB);

    // ---- P3: per-(block,group) bases ----
    for (int id = gid; id < NSUB * NGROUP; id += GT) {
        int bb = id / NGROUP, g = id - bb * NGROUP;
        int run = goff[g];
        for (int b2 = 0; b2 < bb; ++b2) run += partial2[b2 * NGROUP + g];
        int b0 = bb * BS, b1 = (b0 + BS < NB) ? b0 + BS : NB;
        for (int b = b0; b < b1; ++b) {
            pbase[b * NGROUP + g] = run;
            run += partial[b * NGROUP + g];
        }
    }
    gsync(arr, rel, 3, NB);

    // ---- P4: reorder into group-64 CSR with 6-bit node tags ----
    {
        int* base = (int*)smem;                   // NGROUP
        int* cnt  = base + NGROUP;                // NGROUP
        for (int g = tid; g < NGROUP; g += 512) {
            base[g] = pbase[bid * NGROUP + g]; cnt[g] = 0;
        }
        __syncthreads();
        float rsv = rs[0], sg = sigma[0];
        int2* metaT = (int2*)bufA;
        for (int i = ebeg + tid; i < eend; i += 512) {
            float r  = e[i];
            float d  = r - rsv;
            float gauss = expf(-(d * d) / (sg * sg));
            float cut   = 0.5f * cosf(r * (float)(M_PI / (double)RCUT));
            cut = (r < RCUT) ? cut : 0.0f;
            float fe = gauss * cut;
            int dn = dst[i];
            int g  = dn >> 6;
            int lr = atomicAdd(&cnt[g], 1);
            metaT[base[g] + lr] = make_int2(src[i] * (DIM * 2) | ((dn & 63) << 24),
                                            __float_as_int(fe));
        }
    }
    gsync(arr, rel, 4, NB);

    // ---- P5: 64-bin counting sort per group -> node-exact CSR ----
    for (int g = bid; g < NGROUP; g += NB) {
        __syncthreads();                          // protect smem reuse across iters
        int* c64 = (int*)smem; int* b64 = c64 + 64; int* cu64 = b64 + 64;
        const int2* metaT = (const int2*)bufA;
        int sbeg = goff[g], send = goff[g + 1];
        if (tid < 64) c64[tid] = 0;
        __syncthreads();
        for (int i = sbeg + tid; i < send; i += 512)
            atomicAdd(&c64[(metaT[i].x >> 24) & 63], 1);
        __syncthreads();
        if (tid == 0) {
            int run = 0;
            #pragma unroll
            for (int t = 0; t < 64; ++t) { b64[t] = run; cu64[t] = run; run += c64[t]; }
        }
        __syncthreads();
        if (tid < 64) {
            int node = g * 64 + tid;
            if (node <= N_NODES) off[node] = sbeg + b64[tid];
        }
        __syncthreads();
        for (int i = sbeg + tid; i < send; i += 512) {
            int2 m = metaT[i];
            int tag = (m.x >> 24) & 63;
            int lr = atomicAdd(&cu64[tag], 1);
            meta[sbeg + lr] = make_int2(m.x & 0x00FFFFFF, m.y);
        }
    }
    gsync(arr, rel, 5, NB);

    // ---- P6..P8: three fused gather+GEMM layers ----
    unsigned short* xlds = (unsigned short*)smem;
    for (int L = 0; L < 3; ++L) {
        const unsigned short* curp = (L == 0) ? bufV : ((L == 1) ? bufB : bufA);
        unsigned short* outb = (L == 0) ? bufB : bufA;
        for (int g = bid; g < NGROUP; g += NB) {
            __syncthreads();                      // xlds reuse across iters
            layer_body(curp, bufV, meta, off, wfrag, Ab,
                       outb, out, (L == 2) ? 1 : 0, g, xlds);
        }
        if (L < 2) gsync(arr, rel, 6 + L, NB);
    }
}

// ---------------------------------------------------------------------------
extern "C" void kernel_launch(void* const* d_in, const int* in_sizes, int n_in,
                              void* d_out, int out_size, void* d_ws, size_t ws_size,
                              hipStream_t stream) {
    const float* v     = (const float*)d_in[0];
    const float* e     = (const float*)d_in[1];
    const int*   src   = (const int*)  d_in[2];
    const int*   dst   = (const int*)  d_in[3];
    const float* Aw    = (const float*)d_in[4];
    const float* Ab    = (const float*)d_in[5];
    const float* rs    = (const float*)d_in[6];
    const float* sigma = (const float*)d_in[7];
    float* out = (float*)d_out;

    // ---- workspace layout (~51.6 MB) ----
    char* p = (char*)d_ws;
    int2*           meta  = (int2*)p;            p += (size_t)N_EDGES * 8;       // 12.8 MB (final CSR)
    unsigned short* bufV  = (unsigned short*)p;  p += (size_t)N_PAD * DIM * 2;   // 12.81 MB (pristine bf16 v)
    unsigned short* bufA  = (unsigned short*)p;  p += (size_t)N_PAD * DIM * 2;   // 12.81 MB (metaT / L1 out)
    unsigned short* bufB  = (unsigned short*)p;  p += (size_t)N_PAD * DIM * 2;   // 12.81 MB (partials / L0 out)
    uint4*          wfrag = (uint4*)p;           p += 2048 * 16;                 //  32 KB
    int*            off   = (int*)p;             p += (size_t)(N_NODES + 1) * 4;
    int*            goff  = (int*)p;             p += (NGROUP + 2) * 4;
    int*            bar   = (int*)p;             p += (NPHASE * 64 * BSTRIDE + BSTRIDE) * 4;
    int*            rel   = bar + NPHASE * 64 * BSTRIDE;   // own cacheline
    // aliases inside bufB (dead before L0's first write):
    int* partial  = (int*)bufB;                  // [MAXNB][NGROUP] = 3.2 MB
    int* partial2 = partial + MAXNB * NGROUP;    // [NSUB][NGROUP]  = 50 KB
    int* pbase    = partial2 + NSUB * NGROUP;    // [MAXNB][NGROUP] = 3.2 MB

    static int maxblk = 0;
    if (maxblk == 0) {
        if (hipOccupancyMaxActiveBlocksPerMultiprocessor(&maxblk, mega_kernel, 512, 0)
                != hipSuccess || maxblk <= 0)
            maxblk = 2;   // conservative floor
    }
    int nb = maxblk * 256;          // 256 CUs on MI355X
    if (nb > NGROUP) nb = NGROUP;   // also guarantees nb <= MAXNB

    hipMemsetAsync(bar, 0, (NPHASE * 64 * BSTRIDE + BSTRIDE) * 4, stream);
    mega_kernel<<<nb, 512, 0, stream>>>(
        v, e, src, dst, Aw, Ab, rs, sigma, out,
        meta, bufV, bufA, bufB, wfrag, off, goff,
        partial, partial2, pbase, bar, rel);
}

// Round 4
// 332.663 us; speedup vs baseline: 2.7298x; 2.0944x over previous
//
#include <hip/hip_runtime.h>
#include <math.h>

#define N_NODES 50000
#define N_PAD   50048              // rows padded to multiple of 64
#define N_EDGES 1600000
#define DIM     128
#define RCUT    5.0f
#define NGROUP  (N_PAD / 64)       // 782 groups of 64 nodes
#define NB_PRE  512
#define CH_PRE  (N_EDGES / NB_PRE) // 3125 edges per preprocessing block
#define NB_CONV 6250               // convert blocks in preA
#define NB_WPREP 8                 // wprep blocks in preA
#define NB_SUB  8                  // b-subchunks for ktot2/kbase2
#define B_SUB   (NB_PRE / NB_SUB)  // 64
#define XPAD    136                // LDS X tile row stride in bf16 (272 B)
#define NTILE   (N_PAD / 16)       // 3128 16-node tiles for layer12

typedef __attribute__((ext_vector_type(8))) __bf16 bf16x8;
typedef __attribute__((ext_vector_type(4))) float  f32x4;

// ---------------- bf16 helpers ----------------
__device__ __forceinline__ float bf_lo(unsigned int u) { return __uint_as_float(u << 16); }
__device__ __forceinline__ float bf_hi(unsigned int u) { return __uint_as_float(u & 0xffff0000u); }
__device__ __forceinline__ unsigned short f2bf(float x) {
    unsigned int u = __float_as_uint(x);
    u += 0x7fffu + ((u >> 16) & 1u);   // round-to-nearest-even
    return (unsigned short)(u >> 16);
}

// ---------------- preA: convert v->bf16  |  W->frags  |  group-64 histogram ---
__global__ __launch_bounds__(256) void preA_kernel(
        const float* __restrict__ v, unsigned short* __restrict__ vb,
        const float* __restrict__ Aw, uint4* __restrict__ wfrag,
        const int* __restrict__ dst, int* __restrict__ partial) {
    int b = blockIdx.x;
    if (b < NB_CONV) {
        int i = b * 256 + threadIdx.x;           // exactly N_NODES*DIM/4
        float4 x = ((const float4*)v)[i];
        uint2 o;
        o.x = (unsigned)f2bf(x.x) | ((unsigned)f2bf(x.y) << 16);
        o.y = (unsigned)f2bf(x.z) | ((unsigned)f2bf(x.w) << 16);
        ((uint2*)vb)[i] = o;
    } else if (b < NB_CONV + NB_WPREP) {
        int t = (b - NB_CONV) * 256 + threadIdx.x;   // 0..2047
        int lane = t & 63, nt = (t >> 6) & 7, kk = t >> 9;
        int n  = nt * 16 + (lane & 15);
        int k0 = kk * 32 + (lane >> 4) * 8;
        unsigned short h[8];
        #pragma unroll
        for (int i = 0; i < 8; ++i) h[i] = f2bf(Aw[n * DIM + k0 + i]);
        uint4 o;
        o.x = h[0] | ((unsigned)h[1] << 16); o.y = h[2] | ((unsigned)h[3] << 16);
        o.z = h[4] | ((unsigned)h[5] << 16); o.w = h[6] | ((unsigned)h[7] << 16);
        wfrag[t] = o;
    } else {
        __shared__ int h[NGROUP];                // 3.1 KB
        int cb = b - NB_CONV - NB_WPREP, tid = threadIdx.x;
        for (int g = tid; g < NGROUP; g += 256) h[g] = 0;
        __syncthreads();
        int beg = cb * CH_PRE, end = beg + CH_PRE;
        for (int i = beg + tid; i < end; i += 256)
            atomicAdd(&h[dst[i] >> 6], 1);       // LDS atomic
        __syncthreads();
        for (int g = tid; g < NGROUP; g += 256) partial[cb * NGROUP + g] = h[g];
    }
}

// ---------------- partial sums over b-subchunks ----------------
__global__ __launch_bounds__(256) void ktot2_kernel(const int* __restrict__ partial,
                                                    int* __restrict__ partial2) {
    int gb = blockIdx.x & 3, bb = blockIdx.x >> 2;
    int g = gb * 256 + threadIdx.x;
    if (g >= NGROUP) return;
    int s = 0;
    int b0 = bb * B_SUB;
    for (int b = b0; b < b0 + B_SUB; ++b) s += partial[b * NGROUP + g];
    partial2[bb * NGROUP + g] = s;
}

// ---------------- exclusive scan over 782 group totals ----------------
__global__ __launch_bounds__(256) void kscan_kernel(const int* __restrict__ partial2,
                                                    int* __restrict__ goff) {
    __shared__ int part[256];
    int tid = threadIdx.x;
    int i0 = tid * 4;
    int v[4]; int s = 0;
    #pragma unroll
    for (int k = 0; k < 4; ++k) {
        int i = i0 + k; int t = 0;
        if (i < NGROUP) {
            #pragma unroll
            for (int bb = 0; bb < NB_SUB; ++bb) t += partial2[bb * NGROUP + i];
        }
        v[k] = t; s += t;
    }
    part[tid] = s; __syncthreads();
    for (int d = 1; d < 256; d <<= 1) {
        int val = (tid >= d) ? part[tid - d] : 0;
        __syncthreads(); part[tid] += val; __syncthreads();
    }
    int run = (tid == 0) ? 0 : part[tid - 1];
    #pragma unroll
    for (int k = 0; k < 4; ++k) {
        int i = i0 + k;
        if (i < NGROUP) { goff[i] = run; run += v[k]; }
    }
    if (tid == 0) goff[NGROUP] = N_EDGES;
}

// ---------------- per-(block,group) bases ----------------
__global__ __launch_bounds__(256) void kbase2_kernel(const int* __restrict__ partial,
                                                     const int* __restrict__ partial2,
                                                     const int* __restrict__ goff,
                                                     int* __restrict__ pbase) {
    int gb = blockIdx.x & 3, bb = blockIdx.x >> 2;
    int g = gb * 256 + threadIdx.x;
    if (g >= NGROUP) return;
    int run = goff[g];
    for (int b2 = 0; b2 < bb; ++b2) run += partial2[b2 * NGROUP + g];
    int b0 = bb * B_SUB;
    for (int b = b0; b < b0 + B_SUB; ++b) {
        pbase[b * NGROUP + g] = run;
        run += partial[b * NGROUP + g];
    }
}

// ---------------- reorder into group-64 CSR with 6-bit node tags ----------
__global__ __launch_bounds__(512) void reorder_kernel(
        const float* __restrict__ e,
        const int*   __restrict__ src,
        const int*   __restrict__ dst,
        const float* __restrict__ rs,
        const float* __restrict__ sigma,
        const int*   __restrict__ pbase,
        int2* __restrict__ metaT) {
    __shared__ int base[NGROUP];
    __shared__ int cnt[NGROUP];
    int b = blockIdx.x, tid = threadIdx.x;
    for (int g = tid; g < NGROUP; g += 512) { base[g] = pbase[b * NGROUP + g]; cnt[g] = 0; }
    __syncthreads();
    float rsv = rs[0], sg = sigma[0];
    int beg = b * CH_PRE, end = beg + CH_PRE;
    for (int i = beg + tid; i < end; i += 512) {
        float r  = e[i];
        float d  = r - rsv;
        float gauss = expf(-(d * d) / (sg * sg));
        float cut   = 0.5f * cosf(r * (float)(M_PI / (double)RCUT));
        cut = (r < RCUT) ? cut : 0.0f;
        float fe = gauss * cut;
        int dn = dst[i];
        int g  = dn >> 6;
        int lr = atomicAdd(&cnt[g], 1);          // LDS atomic
        metaT[base[g] + lr] = make_int2(src[i] * (DIM * 2) | ((dn & 63) << 24),
                                        __float_as_int(fe));
    }
}

// ---------------- shared gather inner loop ----------------
#define EDGE2(mx, mf, rr)                                        \
    do {                                                         \
        float ff = __int_as_float(mf);                           \
        a0 = fmaf(ff, bf_lo(rr), a0);                            \
        a1 = fmaf(ff, bf_hi(rr), a1);                            \
    } while (0)

__device__ __forceinline__ void gather_node(
        const int2* __restrict__ meta, const char* basec,
        int beg, int end, float& a0, float& a1) {
    int c = beg;
    if ((c & 1) && c < end) {
        int2 m = meta[c];
        unsigned rr = *(const unsigned*)(basec + (unsigned)m.x);
        EDGE2(m.x, m.y, rr);
        ++c;
    }
    for (; c + 16 <= end; c += 16) {
        int4 m0 = *(const int4*)(meta + c);
        int4 m1 = *(const int4*)(meta + c + 2);
        int4 m2 = *(const int4*)(meta + c + 4);
        int4 m3 = *(const int4*)(meta + c + 6);
        int4 m4 = *(const int4*)(meta + c + 8);
        int4 m5 = *(const int4*)(meta + c + 10);
        int4 m6 = *(const int4*)(meta + c + 12);
        int4 m7 = *(const int4*)(meta + c + 14);
        unsigned r0  = *(const unsigned*)(basec + (unsigned)m0.x);
        unsigned r1  = *(const unsigned*)(basec + (unsigned)m0.z);
        unsigned r2  = *(const unsigned*)(basec + (unsigned)m1.x);
        unsigned r3  = *(const unsigned*)(basec + (unsigned)m1.z);
        unsigned r4  = *(const unsigned*)(basec + (unsigned)m2.x);
        unsigned r5  = *(const unsigned*)(basec + (unsigned)m2.z);
        unsigned r6  = *(const unsigned*)(basec + (unsigned)m3.x);
        unsigned r7  = *(const unsigned*)(basec + (unsigned)m3.z);
        unsigned r8  = *(const unsigned*)(basec + (unsigned)m4.x);
        unsigned r9  = *(const unsigned*)(basec + (unsigned)m4.z);
        unsigned r10 = *(const unsigned*)(basec + (unsigned)m5.x);
        unsigned r11 = *(const unsigned*)(basec + (unsigned)m5.z);
        unsigned r12 = *(const unsigned*)(basec + (unsigned)m6.x);
        unsigned r13 = *(const unsigned*)(basec + (unsigned)m6.z);
        unsigned r14 = *(const unsigned*)(basec + (unsigned)m7.x);
        unsigned r15 = *(const unsigned*)(basec + (unsigned)m7.z);
        EDGE2(m0.x, m0.y, r0);  EDGE2(m0.z, m0.w, r1);
        EDGE2(m1.x, m1.y, r2);  EDGE2(m1.z, m1.w, r3);
        EDGE2(m2.x, m2.y, r4);  EDGE2(m2.z, m2.w, r5);
        EDGE2(m3.x, m3.y, r6);  EDGE2(m3.z, m3.w, r7);
        EDGE2(m4.x, m4.y, r8);  EDGE2(m4.z, m4.w, r9);
        EDGE2(m5.x, m5.y, r10); EDGE2(m5.z, m5.w, r11);
        EDGE2(m6.x, m6.y, r12); EDGE2(m6.z, m6.w, r13);
        EDGE2(m7.x, m7.y, r14); EDGE2(m7.z, m7.w, r15);
    }
    if (c + 8 <= end) {
        int4 m0 = *(const int4*)(meta + c);
        int4 m1 = *(const int4*)(meta + c + 2);
        int4 m2 = *(const int4*)(meta + c + 4);
        int4 m3 = *(const int4*)(meta + c + 6);
        unsigned r0 = *(const unsigned*)(basec + (unsigned)m0.x);
        unsigned r1 = *(const unsigned*)(basec + (unsigned)m0.z);
        unsigned r2 = *(const unsigned*)(basec + (unsigned)m1.x);
        unsigned r3 = *(const unsigned*)(basec + (unsigned)m1.z);
        unsigned r4 = *(const unsigned*)(basec + (unsigned)m2.x);
        unsigned r5 = *(const unsigned*)(basec + (unsigned)m2.z);
        unsigned r6 = *(const unsigned*)(basec + (unsigned)m3.x);
        unsigned r7 = *(const unsigned*)(basec + (unsigned)m3.z);
        EDGE2(m0.x, m0.y, r0); EDGE2(m0.z, m0.w, r1);
        EDGE2(m1.x, m1.y, r2); EDGE2(m1.z, m1.w, r3);
        EDGE2(m2.x, m2.y, r4); EDGE2(m2.z, m2.w, r5);
        EDGE2(m3.x, m3.y, r6); EDGE2(m3.z, m3.w, r7);
        c += 8;
    }
    for (; c < end; ++c) {
        int2 m = meta[c];
        unsigned rr = *(const unsigned*)(basec + (unsigned)m.x);
        EDGE2(m.x, m.y, rr);
    }
}

// ---------------- layer 0: tagsort + gather + GEMM (one group per block) ---
__global__ __launch_bounds__(512) void layer0_kernel(
        const unsigned short* __restrict__ cur,   // bf16 (= vb for L0)
        const unsigned short* __restrict__ vb,
        const int2*  __restrict__ metaT,          // group-CSR, tagged
        const int*   __restrict__ goff,
        int2* __restrict__ meta,                  // out: node-exact CSR
        int*  __restrict__ off,                   // out: node offsets
        const uint4* __restrict__ wfrag,
        const float* __restrict__ bias,
        unsigned short* __restrict__ out_bf) {
    __shared__ unsigned short xlds[64 * XPAD];    // 17408 B
    __shared__ int c64[64], b64[65], cu64[64];
    int tid = threadIdx.x;
    int wv  = tid >> 6, lane = tid & 63;
    int g   = blockIdx.x;
    int sbeg = goff[g], send = goff[g + 1];

    // ---- tagsort: 64-bin count + scan + scatter into node-exact meta ----
    if (tid < 64) c64[tid] = 0;
    __syncthreads();
    for (int i = sbeg + tid; i < send; i += 512)
        atomicAdd(&c64[(metaT[i].x >> 24) & 63], 1);
    __syncthreads();
    if (tid == 0) {
        int run = 0;
        #pragma unroll
        for (int t = 0; t < 64; ++t) { b64[t] = run; cu64[t] = run; run += c64[t]; }
        b64[64] = run;
    }
    __syncthreads();
    if (tid < 64) {
        int node = g * 64 + tid;
        if (node <= N_NODES) off[node] = sbeg + b64[tid];
    }
    for (int i = sbeg + tid; i < send; i += 512) {
        int2 m = metaT[i];
        int tag = (m.x >> 24) & 63;
        int lr = atomicAdd(&cu64[tag], 1);
        meta[sbeg + lr] = make_int2(m.x & 0x00FFFFFF, m.y);
    }
    __syncthreads();   // meta writes drained to L2; b64 stable

    // ---- gather (offsets from LDS b64) ----
    int n0 = g * 64 + wv * 8;
    int myoff = 0;
    if (lane < 9) myoff = sbeg + b64[wv * 8 + lane];
    const char* basec = (const char*)cur + lane * 4;

    #pragma unroll 1
    for (int q = 0; q < 8; ++q) {
        int nl = wv * 8 + q;
        int n  = n0 + q;
        float a0 = 0.f, a1 = 0.f;
        if (n < N_NODES) {
            unsigned vv = *(const unsigned*)((const char*)vb + (size_t)n * (DIM * 2) + lane * 4);
            a0 = bf_lo(vv); a1 = bf_hi(vv);
            int beg = __builtin_amdgcn_readlane(myoff, q);
            int end = __builtin_amdgcn_readlane(myoff, q + 1);
            gather_node(meta, basec, beg, end, a0, a1);
        }
        *(unsigned*)(xlds + nl * XPAD + lane * 2) =
            (unsigned)f2bf(a0) | ((unsigned)f2bf(a1) << 16);
    }
    __syncthreads();

    // ---- GEMM: wave wv -> rows (wv>>1)*16..+15, col-half (wv&1) ----
    int quad = lane >> 4, l16 = lane & 15;
    int rb = wv >> 1, nh = wv & 1;
    f32x4 acc[4];
    #pragma unroll
    for (int j = 0; j < 4; ++j) acc[j] = (f32x4){0.f, 0.f, 0.f, 0.f};

    const unsigned short* xp = xlds + (rb * 16 + l16) * XPAD + quad * 8;
    #pragma unroll
    for (int kk = 0; kk < 4; ++kk) {
        bf16x8 af = *(const bf16x8*)(xp + kk * 32);
        #pragma unroll
        for (int j = 0; j < 4; ++j) {
            uint4 w = wfrag[(kk * 8 + nh * 4 + j) * 64 + lane];
            bf16x8 bfr = __builtin_bit_cast(bf16x8, w);
            acc[j] = __builtin_amdgcn_mfma_f32_16x16x32_bf16(af, bfr, acc[j], 0, 0, 0);
        }
    }

    int orow0 = g * 64 + rb * 16 + quad * 4;
    #pragma unroll
    for (int j = 0; j < 4; ++j) {
        int col = (nh * 4 + j) * 16 + l16;
        float b = bias[col];
        #pragma unroll
        for (int r = 0; r < 4; ++r) {
            int orow = orow0 + r;
            if (orow < N_NODES)
                out_bf[(size_t)orow * DIM + col] = f2bf(fmaxf(acc[j][r] + b, 0.f));
        }
    }
}

// ---------------- layers 1/2: 2-wave 16-node fused gather+GEMM ----------------
__global__ __launch_bounds__(128, 8) void layer12_kernel(
        const unsigned short* __restrict__ cur,
        const unsigned short* __restrict__ vb,
        const int2*  __restrict__ meta,
        const int*   __restrict__ off,
        const uint4* __restrict__ wfrag,
        const float* __restrict__ bias,
        unsigned short* __restrict__ out_bf,
        float* __restrict__ out_f,
        int last) {
    __shared__ unsigned short xlds[16 * XPAD];    // 4352 B
    int tid = threadIdx.x;
    int wv  = tid >> 6, lane = tid & 63;          // wv in {0,1}
    int tile = blockIdx.x;
    int n0  = tile * 16 + wv * 8;

    int offidx = n0 + ((lane < 9) ? lane : 8);
    if (offidx > N_NODES) offidx = N_NODES;
    int myoff = off[offidx];
    const char* basec = (const char*)cur + lane * 4;

    #pragma unroll 1
    for (int q = 0; q < 8; ++q) {
        int nl = wv * 8 + q;
        int n  = n0 + q;
        float a0 = 0.f, a1 = 0.f;
        if (n < N_NODES) {
            unsigned vv = *(const unsigned*)((const char*)vb + (size_t)n * (DIM * 2) + lane * 4);
            a0 = bf_lo(vv); a1 = bf_hi(vv);
            int beg = __builtin_amdgcn_readlane(myoff, q);
            int end = __builtin_amdgcn_readlane(myoff, q + 1);
            gather_node(meta, basec, beg, end, a0, a1);
        }
        *(unsigned*)(xlds + nl * XPAD + lane * 2) =
            (unsigned)f2bf(a0) | ((unsigned)f2bf(a1) << 16);
    }
    __syncthreads();

    // ---- GEMM: both waves cover all 16 rows; wave = col-half ----
    int quad = lane >> 4, l16 = lane & 15;
    f32x4 acc[4];
    #pragma unroll
    for (int j = 0; j < 4; ++j) acc[j] = (f32x4){0.f, 0.f, 0.f, 0.f};

    const unsigned short* xp = xlds + l16 * XPAD + quad * 8;
    #pragma unroll
    for (int kk = 0; kk < 4; ++kk) {
        bf16x8 af = *(const bf16x8*)(xp + kk * 32);
        #pragma unroll
        for (int j = 0; j < 4; ++j) {
            uint4 w = wfrag[(kk * 8 + wv * 4 + j) * 64 + lane];
            bf16x8 bfr = __builtin_bit_cast(bf16x8, w);
            acc[j] = __builtin_amdgcn_mfma_f32_16x16x32_bf16(af, bfr, acc[j], 0, 0, 0);
        }
    }

    int orow0 = tile * 16 + quad * 4;
    #pragma unroll
    for (int j = 0; j < 4; ++j) {
        int col = (wv * 4 + j) * 16 + l16;
        float b = bias[col];
        #pragma unroll
        for (int r = 0; r < 4; ++r) {
            int orow = orow0 + r;
            if (orow < N_NODES) {
                float val = fmaxf(acc[j][r] + b, 0.f);
                if (last) out_f[(size_t)orow * DIM + col] = val;
                else      out_bf[(size_t)orow * DIM + col] = f2bf(val);
            }
        }
    }
}

// ---------------------------------------------------------------------------
extern "C" void kernel_launch(void* const* d_in, const int* in_sizes, int n_in,
                              void* d_out, int out_size, void* d_ws, size_t ws_size,
                              hipStream_t stream) {
    const float* v     = (const float*)d_in[0];
    const float* e     = (const float*)d_in[1];
    const int*   src   = (const int*)  d_in[2];
    const int*   dst   = (const int*)  d_in[3];
    const float* Aw    = (const float*)d_in[4];
    const float* Ab    = (const float*)d_in[5];
    const float* rs    = (const float*)d_in[6];
    const float* sigma = (const float*)d_in[7];
    float* out = (float*)d_out;

    // ---- workspace layout (~51.5 MB) ----
    char* p = (char*)d_ws;
    int2*           meta  = (int2*)p;            p += (size_t)N_EDGES * 8;       // 12.8 MB (final CSR)
    unsigned short* bufV  = (unsigned short*)p;  p += (size_t)N_PAD * DIM * 2;   // 12.81 MB (pristine bf16 v)
    unsigned short* bufA  = (unsigned short*)p;  p += (size_t)N_PAD * DIM * 2;   // 12.81 MB (metaT / L1 out)
    unsigned short* bufB  = (unsigned short*)p;  p += (size_t)N_PAD * DIM * 2;   // 12.81 MB (partials / L0 out)
    uint4*          wfrag = (uint4*)p;           p += 2048 * 16;                 //  32 KB
    int*            off   = (int*)p;             p += (size_t)(N_NODES + 1) * 4;
    int*            goff  = (int*)p;             p += (NGROUP + 2) * 4;
    // aliases (dead before host buffer's first real write):
    int2* metaT    = (int2*)bufA;                // unsorted group-CSR, dead after layer0
    int*  partial  = (int*)bufB;                 // NB_PRE*NGROUP*4 = 1.6 MB
    int*  pbase    = partial + NB_PRE * NGROUP;  // 1.6 MB, dead after reorder
    int*  partial2 = pbase + NB_PRE * NGROUP;    // NB_SUB*NGROUP*4 = 25 KB

    preA_kernel<<<NB_CONV + NB_WPREP + NB_PRE, 256, 0, stream>>>(
        v, bufV, Aw, wfrag, dst, partial);
    ktot2_kernel<<<4 * NB_SUB, 256, 0, stream>>>(partial, partial2);
    kscan_kernel<<<1, 256, 0, stream>>>(partial2, goff);
    kbase2_kernel<<<4 * NB_SUB, 256, 0, stream>>>(partial, partial2, goff, pbase);
    reorder_kernel<<<NB_PRE, 512, 0, stream>>>(e, src, dst, rs, sigma, pbase, metaT);

    // L0: tagsort + gather(bufV) + gemm -> bufB   (consumes metaT in bufA)
    layer0_kernel<<<NGROUP, 512, 0, stream>>>(
        bufV, bufV, metaT, goff, meta, off, wfrag, Ab, bufB);
    // L1: gather(bufB) + gemm -> bufA
    layer12_kernel<<<NTILE, 128, 0, stream>>>(
        bufB, bufV, meta, off, wfrag, Ab, bufA, nullptr, 0);
    // L2: gather(bufA) + gemm -> out (fp32)
    layer12_kernel<<<NTILE, 128, 0, stream>>>(
        bufA, bufV, meta, off, wfrag, Ab, nullptr, out, 1);
}